// Round 9
// baseline (196.383 us; speedup 1.0000x reference)
//
#include <hip/hip_runtime.h>

#define TD 10
#define NCOL 256
#define HALF 128                  // cols per thread (half a row)
#define GCOLS 16                  // cols per group (4 float4)
#define ROWS_PER_BLOCK 64         // 128 threads = 2 waves = 2 col-halves x 64 rows

// ---- DFS fold over one level-1 subtree (512 leaves), 16-leaf terminal groups ----
// p/q indexed by ABSOLUTE level; IDX is the absolute node index at LEVEL.
// g[k] = t6*t7*t8*t9, k = (b6<<3)|(b7<<2)|(b8<<1)|b9.
template <int LEVEL, int IDX>
__device__ __forceinline__ void fold(const float* __restrict__ lv,
                                     const float (&p)[TD], const float (&q)[TD],
                                     const float (&g)[16],
                                     float prefix, float& acc) {
  if constexpr (LEVEL == TD - 4) {
    const float* l16 = lv + 16 * IDX;
    float t = l16[0] * g[0];
#pragma unroll
    for (int k = 1; k < 16; ++k) t = fmaf(l16[k], g[k], t);
    acc = fmaf(prefix, t, acc);
  } else {
    fold<LEVEL + 1, 2 * IDX>(lv, p, q, g, prefix * q[LEVEL], acc);
    fold<LEVEL + 1, 2 * IDX + 1>(lv, p, q, g, prefix * p[LEVEL], acc);
  }
}

__global__ void __launch_bounds__(128, 6)   // 6 waves/SIMD -> 85 VGPR budget, no spill
odt_kernel(const float* __restrict__ x, const float* __restrict__ W,
           const float* __restrict__ bias, const float* __restrict__ lv,
           float* __restrict__ out) {
  // 2 waves/block: wave h handles cols [h*128, h*128+128) of rows blockIdx*64+lane.
  __shared__ float ps[2][ROWS_PER_BLOCK][11];  // partials, stride 11 = conflict-free
  __shared__ float accs[2][ROWS_PER_BLOCK];

  const int lane = threadIdx.x & 63;
  const int h = __builtin_amdgcn_readfirstlane(threadIdx.x >> 6);  // SGPR
  const int row = blockIdx.x * ROWS_PER_BLOCK + lane;
  const float* __restrict__ xr = x + (size_t)row * NCOL + h * HALF;

  float sums[TD];
#pragma unroll
  for (int d = 0; d < TD; ++d) sums[d] = 0.0f;

  // NO arrays, NO address-taking on vector regs — spill-proof by construction.
  float4 A0, A1, A2, A3, B0, B1, B2, B3;

#define LOADG(V0, V1, V2, V3, G)                                   \
  V0 = *(const float4*)(xr + (G) * GCOLS + 0);                     \
  V1 = *(const float4*)(xr + (G) * GCOLS + 4);                     \
  V2 = *(const float4*)(xr + (G) * GCOLS + 8);                     \
  V3 = *(const float4*)(xr + (G) * GCOLS + 12);

  auto fmacol = [&](float xe, int col) {
#pragma unroll
    for (int d = 0; d < TD; ++d)
      sums[d] = fmaf(xe, W[col * TD + d], sums[d]);  // col wave-uniform -> s_load
  };
#define CONS4(V, CB)                                               \
  fmacol(V.x, (CB) + 0); fmacol(V.y, (CB) + 1);                    \
  fmacol(V.z, (CB) + 2); fmacol(V.w, (CB) + 3);
#define CONSG(V0, V1, V2, V3, G)                                   \
  CONS4(V0, h * HALF + (G) * GCOLS + 0)                            \
  CONS4(V1, h * HALF + (G) * GCOLS + 4)                            \
  CONS4(V2, h * HALF + (G) * GCOLS + 8)                            \
  CONS4(V3, h * HALF + (G) * GCOLS + 12)

  // software pipeline: next group's 4 loads in flight across current's 160 FMAs
  LOADG(A0, A1, A2, A3, 0)
  LOADG(B0, B1, B2, B3, 1)
  CONSG(A0, A1, A2, A3, 0)
  LOADG(A0, A1, A2, A3, 2)
  CONSG(B0, B1, B2, B3, 1)
  LOADG(B0, B1, B2, B3, 3)
  CONSG(A0, A1, A2, A3, 2)
  LOADG(A0, A1, A2, A3, 4)
  CONSG(B0, B1, B2, B3, 3)
  LOADG(B0, B1, B2, B3, 5)
  CONSG(A0, A1, A2, A3, 4)
  LOADG(A0, A1, A2, A3, 6)
  CONSG(B0, B1, B2, B3, 5)
  LOADG(B0, B1, B2, B3, 7)
  CONSG(A0, A1, A2, A3, 6)
  CONSG(B0, B1, B2, B3, 7)
#undef LOADG
#undef CONS4
#undef CONSG

  // publish partials (stride-11 rows: lanes spread across all 32 banks)
#pragma unroll
  for (int d = 0; d < TD; ++d) ps[h][lane][d] = sums[d];
  __syncthreads();

  // combine halves + sigmoid (duplicated across the pair — cheap)
  float p[TD], q[TD];
#pragma unroll
  for (int d = 0; d < TD; ++d) {
    const float tot = bias[d] + sums[d] + ps[h ^ 1][lane][d];
    const float sg = 1.0f / (1.0f + __expf(-tot));
    p[d] = sg;
    q[d] = 1.0f - sg;
  }

  // g[k] = t6*t7*t8*t9 products for a 16-leaf group
  float g[16];
  {
    float hA[4], hB[4];
    hA[0] = q[6] * q[7]; hA[1] = q[6] * p[7]; hA[2] = p[6] * q[7]; hA[3] = p[6] * p[7];
    hB[0] = q[8] * q[9]; hB[1] = q[8] * p[9]; hB[2] = p[8] * q[9]; hB[3] = p[8] * p[9];
#pragma unroll
    for (int o = 0; o < 16; ++o) g[o] = hA[o >> 2] * hB[o & 3];
  }

  // each col-half folds one level-1 subtree (~690 ops); h is SGPR -> no divergence
  float acc = 0.0f;
  if (h == 0) fold<1, 0>(lv, p, q, g, q[0], acc);
  else        fold<1, 1>(lv, p, q, g, p[0], acc);
  accs[h][lane] = acc;
  __syncthreads();

  if (h == 0)                                   // wave 0: coalesced 256B stores
    out[row] = accs[0][lane] + accs[1][lane];
}

extern "C" void kernel_launch(void* const* d_in, const int* in_sizes, int n_in,
                              void* d_out, int out_size, void* d_ws, size_t ws_size,
                              hipStream_t stream) {
  const float* x = (const float*)d_in[0];
  const float* W = (const float*)d_in[1];
  const float* b = (const float*)d_in[2];
  const float* lv = (const float*)d_in[3];
  float* out = (float*)d_out;

  const int batch = in_sizes[0] / NCOL;          // 262144
  const int grid = batch / ROWS_PER_BLOCK;       // 4096 blocks; 12/CU resident
  odt_kernel<<<grid, 128, 0, stream>>>(x, W, b, lv, out);
}

// Round 10
// 96.656 us; speedup vs baseline: 2.0318x; 2.0318x over previous
//
#include <hip/hip_runtime.h>

#define TD 10
#define NCOL 256
#define HALF 128                  // cols per thread (half a row)
#define ROWS_PER_BLOCK 128        // 256 threads = 2 threads/row

// ---- DFS fold over one level-1 subtree (512 leaves), 8-leaf terminal groups ----
// p/q indexed by ABSOLUTE level; IDX is the absolute node index at LEVEL.
// g[k] = t7*t8*t9, k = (b7<<2)|(b8<<1)|b9  (8 regs, not 16 -> low fold live-set).
template <int LEVEL, int IDX>
__device__ __forceinline__ void fold(const float* __restrict__ lv,
                                     const float (&p)[TD], const float (&q)[TD],
                                     const float (&g)[8],
                                     float prefix, float& acc) {
  if constexpr (LEVEL == TD - 3) {
    const float* l8 = lv + 8 * IDX;
    float t = l8[0] * g[0];
#pragma unroll
    for (int k = 1; k < 8; ++k) t = fmaf(l8[k], g[k], t);
    acc = fmaf(prefix, t, acc);
  } else {
    fold<LEVEL + 1, 2 * IDX>(lv, p, q, g, prefix * q[LEVEL], acc);
    fold<LEVEL + 1, 2 * IDX + 1>(lv, p, q, g, prefix * p[LEVEL], acc);
  }
}

__global__ void __launch_bounds__(256, 8)   // 8 waves/SIMD; live-set sized ~38 VGPR
odt_kernel(const float* __restrict__ x, const float* __restrict__ W,
           const float* __restrict__ bias, const float* __restrict__ lv,
           float* __restrict__ out) {
  // waves 0,1: col-half 0; waves 2,3: col-half 1. r = (w&1)*64+lane.
  __shared__ float ps[2][ROWS_PER_BLOCK][11];  // partials, stride 11 = conflict-free
  __shared__ float accs[2][ROWS_PER_BLOCK];

  const int lane = threadIdx.x & 63;
  const int w = threadIdx.x >> 6;
  const int h = __builtin_amdgcn_readfirstlane(w >> 1);  // SGPR -> W stays s_load
  const int r = (w & 1) * 64 + lane;
  const int row = blockIdx.x * ROWS_PER_BLOCK + r;
  const float* __restrict__ xr = x + (size_t)row * NCOL + h * HALF;

  float sums[TD];
#pragma unroll
  for (int d = 0; d < TD; ++d) sums[d] = 0.0f;

  // 2-deep ping-pong, 8 cols (2 float4) per group => only 16 VGPRs of buffer.
  // sched_barrier(0) after each block pins program order: the scheduler cannot
  // hoist loads across groups and blow up live ranges (the R7-R9 spill cause).
  float4 A0, A1, B0, B1;

#define LOADG(V0, V1, G)                                           \
  V0 = *(const float4*)(xr + (G) * 8);                             \
  V1 = *(const float4*)(xr + (G) * 8 + 4);                         \
  __builtin_amdgcn_sched_barrier(0);

  auto fmacol = [&](float xe, int col) {
#pragma unroll
    for (int d = 0; d < TD; ++d)
      sums[d] = fmaf(xe, W[col * TD + d], sums[d]);  // col wave-uniform -> s_load
  };
#define CONS4(V, CB)                                               \
  fmacol(V.x, (CB) + 0); fmacol(V.y, (CB) + 1);                    \
  fmacol(V.z, (CB) + 2); fmacol(V.w, (CB) + 3);
#define CONSG(V0, V1, G)                                           \
  CONS4(V0, h * HALF + (G) * 8)                                    \
  CONS4(V1, h * HALF + (G) * 8 + 4)                                \
  __builtin_amdgcn_sched_barrier(0);

  LOADG(A0, A1, 0)
  LOADG(B0, B1, 1)
  CONSG(A0, A1, 0)  LOADG(A0, A1, 2)
  CONSG(B0, B1, 1)  LOADG(B0, B1, 3)
  CONSG(A0, A1, 2)  LOADG(A0, A1, 4)
  CONSG(B0, B1, 3)  LOADG(B0, B1, 5)
  CONSG(A0, A1, 4)  LOADG(A0, A1, 6)
  CONSG(B0, B1, 5)  LOADG(B0, B1, 7)
  CONSG(A0, A1, 6)  LOADG(A0, A1, 8)
  CONSG(B0, B1, 7)  LOADG(B0, B1, 9)
  CONSG(A0, A1, 8)  LOADG(A0, A1, 10)
  CONSG(B0, B1, 9)  LOADG(B0, B1, 11)
  CONSG(A0, A1, 10) LOADG(A0, A1, 12)
  CONSG(B0, B1, 11) LOADG(B0, B1, 13)
  CONSG(A0, A1, 12) LOADG(A0, A1, 14)
  CONSG(B0, B1, 13) LOADG(B0, B1, 15)
  CONSG(A0, A1, 14)
  CONSG(B0, B1, 15)
#undef LOADG
#undef CONS4
#undef CONSG

  // publish partials (stride-11 rows spread lanes across all 32 banks)
#pragma unroll
  for (int d = 0; d < TD; ++d) ps[h][r][d] = sums[d];
  __syncthreads();

  // combine halves + sigmoid (duplicated across the pair — cheap)
  float p[TD], q[TD];
#pragma unroll
  for (int d = 0; d < TD; ++d) {
    const float tot = bias[d] + sums[d] + ps[h ^ 1][r][d];
    const float sg = 1.0f / (1.0f + __expf(-tot));
    p[d] = sg;
    q[d] = 1.0f - sg;
  }

  // g[k] = t7*t8*t9 products for an 8-leaf group (8 regs)
  float g[8];
  {
    const float h00 = q[8] * q[9], h01 = q[8] * p[9];
    const float h10 = p[8] * q[9], h11 = p[8] * p[9];
    g[0] = q[7] * h00; g[1] = q[7] * h01; g[2] = q[7] * h10; g[3] = q[7] * h11;
    g[4] = p[7] * h00; g[5] = p[7] * h01; g[6] = p[7] * h10; g[7] = p[7] * h11;
  }

  // each col-half folds one level-1 subtree (~700 ops); h is SGPR -> no divergence
  float acc = 0.0f;
  if (h == 0) fold<1, 0>(lv, p, q, g, q[0], acc);
  else        fold<1, 1>(lv, p, q, g, p[0], acc);
  accs[h][r] = acc;
  __syncthreads();

  if (h == 0)                                   // waves 0,1: coalesced 256B stores
    out[row] = accs[0][r] + accs[1][r];
}

extern "C" void kernel_launch(void* const* d_in, const int* in_sizes, int n_in,
                              void* d_out, int out_size, void* d_ws, size_t ws_size,
                              hipStream_t stream) {
  const float* x = (const float*)d_in[0];
  const float* W = (const float*)d_in[1];
  const float* b = (const float*)d_in[2];
  const float* lv = (const float*)d_in[3];
  float* out = (float*)d_out;

  const int batch = in_sizes[0] / NCOL;          // 262144
  const int grid = batch / ROWS_PER_BLOCK;       // 2048 blocks = 8/CU = 32 waves/CU
  odt_kernel<<<grid, 256, 0, stream>>>(x, W, b, lv, out);
}